// Round 1
// baseline (250.054 us; speedup 1.0000x reference)
//
#include <hip/hip_runtime.h>
#include <hip/hip_bf16.h>

#define LOG2E 1.4426950408889634f
// reference: mask(-1e9) BEFORE scale(/8); log2e folded into Q pre-scale
#define MASKVAL (-1.25e8f * LOG2E)

typedef __bf16 bf16x8 __attribute__((ext_vector_type(8)));
typedef __bf16 bf16x4 __attribute__((ext_vector_type(4)));
typedef short  shortx4 __attribute__((ext_vector_type(4)));
typedef float  floatx4 __attribute__((ext_vector_type(4)));

__device__ __forceinline__ floatx4 mfma16(bf16x8 a, bf16x8 b, floatx4 c) {
  return __builtin_amdgcn_mfma_f32_16x16x32_bf16(a, b, c, 0, 0, 0);
}

// 16x16x16 bf16 MFMA: B-operand layout (n=l15, k=quad*4+i) == S^T C-tile
// layout -> P feeds PV with zero cross-lane transforms.
__device__ __forceinline__ floatx4 mfma_pv(bf16x4 a, bf16x4 b, floatx4 c) {
#if __has_builtin(__builtin_amdgcn_mfma_f32_16x16x16_bf16)
  return __builtin_amdgcn_mfma_f32_16x16x16_bf16(a, b, c, 0, 0, 0);
#else
  shortx4 as, bs;
  __builtin_memcpy(&as, &a, 8);
  __builtin_memcpy(&bs, &b, 8);
  return __builtin_amdgcn_mfma_f32_16x16x16bf16_1k(as, bs, c, 0, 0, 0);
#endif
}

// async global->LDS, 16B per lane. Dest = wave-uniform base + lane*16.
__device__ __forceinline__ void load_lds16(const __bf16* g, __bf16* l) {
  __builtin_amdgcn_global_load_lds(
      (const __attribute__((address_space(1))) void*)g,
      (__attribute__((address_space(3))) void*)l, 16, 0, 0);
}

// ---------------------------------------------------------------------------
// Fold LoRA into weights, emit W_eff^T bf16 [ncols][1024].  Both weight sets
// in one launch: blockIdx.x < 48 -> qkv (ncols 3072), else proj (ncols 1024).
// ---------------------------------------------------------------------------
__global__ __launch_bounds__(256)
void fold_wt2(const float* __restrict__ Wq, const float* __restrict__ Aq,
              const float* __restrict__ Bq, __bf16* __restrict__ WTq,
              const float* __restrict__ Wp, const float* __restrict__ Ap,
              const float* __restrict__ Bp, __bf16* __restrict__ WTp) {
  __shared__ float tile[64][65];
  __shared__ float sLb[8][64];
  const int bx = blockIdx.x;
  const bool isQ = bx < 48;
  const float* W  = isQ ? Wq : Wp;
  const float* La = isQ ? Aq : Ap;
  const float* Lb = isQ ? Bq : Bp;
  __bf16* WT = isQ ? WTq : WTp;
  const int ncols = isQ ? 3072 : 1024;
  const int nt = (isQ ? bx : bx - 48) * 64;
  const int kt = blockIdx.y * 64;
  const int tid = threadIdx.x;
  const int tx = tid & 63, ty = tid >> 6;

  float rLa[8];
  *(float4*)&rLa[0] = *(const float4*)(La + (size_t)(kt + tx) * 8);
  *(float4*)&rLa[4] = *(const float4*)(La + (size_t)(kt + tx) * 8 + 4);

#pragma unroll
  for (int rep = 0; rep < 2; rep++) {
    int idx = tid + rep * 256;
    sLb[idx >> 6][idx & 63] = Lb[(size_t)(idx >> 6) * ncols + nt + (idx & 63)];
  }
#pragma unroll
  for (int rep = 0; rep < 16; rep++) {
    int i = rep * 4 + ty;
    tile[i][tx] = W[(size_t)(kt + i) * ncols + nt + tx];
  }
  __syncthreads();
#pragma unroll
  for (int rep = 0; rep < 16; rep++) {
    int i = rep * 4 + ty;
    int n = nt + i, k = kt + tx;
    float acc = tile[tx][i];
#pragma unroll
    for (int r = 0; r < 8; r++)
      acc += 2.0f * rLa[r] * sLb[r][i];  // LORA_SCALING = 2
    WT[(size_t)n * 1024 + k] = (__bf16)acc;
  }
}

__global__ __launch_bounds__(256)
void cast_x(const float* __restrict__ x, __bf16* __restrict__ o) {
  int i = blockIdx.x * 256 + threadIdx.x;
  float4 v = ((const float4*)x)[i];
  bf16x4 r = {(__bf16)v.x, (__bf16)v.y, (__bf16)v.z, (__bf16)v.w};
  ((bf16x4*)o)[i] = r;
}

// ---------------------------------------------------------------------------
// Fused QKV projection, swapped orientation: D[p][s] = sum_k WT[p][k] X[s][k].
// 128x128 tiles, BK=64, global_load_lds staging, XOR-swizzled LDS.
// Q channels (p<1024) pre-scaled by 0.125*LOG2E.
// V is written to vtb with keys PERMUTED within each 64-key chunk so the
// flash PV A-fragments are 16B-contiguous: key off (t=off>>4, qd=(off>>2)&3,
// r=off&3) stored at position (t>>1)*32 + qd*8 + (t&1)*4 + r.
// ---------------------------------------------------------------------------
__global__ __launch_bounds__(256)
void gemm_qkv(const __bf16* __restrict__ WT, const __bf16* __restrict__ X,
              const float* __restrict__ bias, __bf16* __restrict__ qk,
              __bf16* __restrict__ vtb) {
  const int K = 1024;
  __shared__ alignas(16) __bf16 As[128 * 64];
  __shared__ alignas(16) __bf16 Bs[128 * 64];
  const int tid = threadIdx.x;
  const int wave = tid >> 6, lane = tid & 63;
  const int wm = wave >> 1, wn = wave & 1;
  const int quad = lane >> 4, l15 = lane & 15;
  const int p0 = blockIdx.y * 128, s0 = blockIdx.x * 128;
  const int srow8 = lane >> 3, sc8 = lane & 7;
  const int sswz = sc8 ^ srow8;

  floatx4 acc[4][4] = {};

  for (int kb = 0; kb < K; kb += 64) {
    __syncthreads();
#pragma unroll
    for (int t = 0; t < 4; t++) {
      int rbase = (wave * 4 + t) * 8;
      int row = rbase + srow8;
      load_lds16(WT + (size_t)(p0 + row) * K + kb + sswz * 8, As + rbase * 64);
      load_lds16(X + (size_t)(s0 + row) * K + kb + sswz * 8, Bs + rbase * 64);
    }
    __syncthreads();
#pragma unroll
    for (int ks = 0; ks < 2; ks++) {
      bf16x8 af[4], bfv[4];
#pragma unroll
      for (int t = 0; t < 4; t++) {
        int ra = wm * 64 + t * 16 + l15;
        int rb = wn * 64 + t * 16 + l15;
        int ch = (ks * 4 + quad) ^ (l15 & 7);
        af[t]  = *(const bf16x8*)(As + ra * 64 + ch * 8);
        bfv[t] = *(const bf16x8*)(Bs + rb * 64 + ch * 8);
      }
#pragma unroll
      for (int mi = 0; mi < 4; mi++)
#pragma unroll
        for (int ni = 0; ni < 4; ni++)
          acc[mi][ni] = mfma16(af[mi], bfv[ni], acc[mi][ni]);
    }
  }

  const float qscale = (p0 < 1024) ? 0.125f * LOG2E : 1.0f;  // block-uniform
#pragma unroll
  for (int mi = 0; mi < 4; mi++) {
#pragma unroll
    for (int ni = 0; ni < 4; ni++) {
      int pb = p0 + wm * 64 + mi * 16 + quad * 4;  // channel base (mult of 4)
      int s  = s0 + wn * 64 + ni * 16 + l15;       // token
      int b = s >> 11, s2 = s & 2047;
      if (p0 < 2048) {  // q/k: uniform per block
        int part = pb >> 10, h = (pb & 1023) >> 6, dhb = pb & 63;
        bf16x4 o = {(__bf16)((acc[mi][ni][0] + bias[pb]) * qscale),
                    (__bf16)((acc[mi][ni][1] + bias[pb + 1]) * qscale),
                    (__bf16)((acc[mi][ni][2] + bias[pb + 2]) * qscale),
                    (__bf16)((acc[mi][ni][3] + bias[pb + 3]) * qscale)};
        *(bf16x4*)(qk + (size_t)part * 4194304 +
                   ((size_t)((b * 16 + h) * 2048 + s2)) * 64 + dhb) = o;
      } else {  // v -> v^T with per-chunk key permutation
        int h = (pb & 1023) >> 6, dhb = pb & 63;
        int off = s2 & 63, t = off >> 4, qd = (off >> 2) & 3, rr = off & 3;
        int ps2 = (s2 & ~63) | ((t >> 1) * 32 + qd * 8 + (t & 1) * 4 + rr);
#pragma unroll
        for (int r = 0; r < 4; r++)
          vtb[((size_t)((b * 16 + h) * 64 + dhb + r)) * 2048 + ps2] =
              (__bf16)(acc[mi][ni][r] + bias[pb + r]);
      }
    }
  }
}

// ---------------------------------------------------------------------------
// Output projection, 64x128 tile: grid (8, 64) = 512 blocks.  fp32 out + bias.
// ---------------------------------------------------------------------------
__global__ __launch_bounds__(256)
void gemm_proj(const __bf16* __restrict__ A, const __bf16* __restrict__ BT,
               const float* __restrict__ bias, float* __restrict__ Cout, int N) {
  const int K = 1024;
  __shared__ alignas(16) __bf16 As[64 * 64];
  __shared__ alignas(16) __bf16 Bs[128 * 64];
  const int tid = threadIdx.x;
  const int wave = tid >> 6, lane = tid & 63;
  const int wm = wave >> 1, wn = wave & 1;
  const int quad = lane >> 4, l15 = lane & 15;
  const int m0 = blockIdx.y * 64, n0 = blockIdx.x * 128;
  const int srow8 = lane >> 3, sc8 = lane & 7;
  const int sswz = sc8 ^ srow8;

  floatx4 acc[2][4] = {};

  for (int kb = 0; kb < K; kb += 64) {
    __syncthreads();
#pragma unroll
    for (int t = 0; t < 2; t++) {
      int rbase = (wave * 2 + t) * 8;
      load_lds16(A + (size_t)(m0 + rbase + srow8) * K + kb + sswz * 8,
                 As + rbase * 64);
    }
#pragma unroll
    for (int t = 0; t < 4; t++) {
      int rbase = (wave * 4 + t) * 8;
      load_lds16(BT + (size_t)(n0 + rbase + srow8) * K + kb + sswz * 8,
                 Bs + rbase * 64);
    }
    __syncthreads();
#pragma unroll
    for (int ks = 0; ks < 2; ks++) {
      bf16x8 af[2], bfv[4];
      int ch = (ks * 4 + quad) ^ (l15 & 7);
#pragma unroll
      for (int t = 0; t < 2; t++)
        af[t] = *(const bf16x8*)(As + (wm * 32 + t * 16 + l15) * 64 + ch * 8);
#pragma unroll
      for (int t = 0; t < 4; t++)
        bfv[t] = *(const bf16x8*)(Bs + (wn * 64 + t * 16 + l15) * 64 + ch * 8);
#pragma unroll
      for (int mi = 0; mi < 2; mi++)
#pragma unroll
        for (int ni = 0; ni < 4; ni++)
          acc[mi][ni] = mfma16(af[mi], bfv[ni], acc[mi][ni]);
    }
  }

#pragma unroll
  for (int mi = 0; mi < 2; mi++)
#pragma unroll
    for (int ni = 0; ni < 4; ni++) {
      int n = n0 + wn * 64 + ni * 16 + l15;
#pragma unroll
      for (int r = 0; r < 4; r++) {
        int m = m0 + wm * 32 + mi * 16 + quad * 4 + r;
        Cout[(size_t)m * N + n] = acc[mi][ni][r] + bias[n];
      }
    }
}

// ---------------------------------------------------------------------------
// Causal flash attention v12: split-K x4, shuffle-free PV with permuted-V
// 16B A-frag loads.  Block = 4 waves = one 32-q strip; wave w takes chunks
// w, w+4, ...  S^T = K·Q^T (16x16x32): C col(l15)=q, row(quad*4+r)=key.
// O^T = V^T·P^T via 16x16x16: P^T C-layout == B-operand layout, V permuted
// so one 16B load feeds two tile A-frags.
// v12 changes vs v11 (theory: latency-bound, MfmaUtil 11.5 / VALUBusy 41 /
// stall ~48%):
//  - K fragments + amask word REGISTER-DOUBLE-BUFFERED one chunk ahead
//    (named kA/kB buffers, static indexing) -> K L2 latency hides under the
//    previous chunk's softmax+PV.
//  - V fragments hoisted into regs right after QK^T, before softmax -> V
//    latency hides under ~700 cyc of softmax VALU.
//  - T13 defer-max (THR=8, log2 domain): skip O-rescale + max update when
//    __all(rm - mrun <= 8); P bounded by 2^8, algebraically exact.
//  - split-K merge parallelized across all 4 waves (each wave combines one
//    dh-tile nd==wave); mbuf grows to [4][36][64] (36.9 KB, still 4 blk/CU).
// NO second __launch_bounds__ arg (R4/R7: waves/EU hint -> spills).
// ---------------------------------------------------------------------------
__global__ __launch_bounds__(256)
void flash_attn(const __bf16* __restrict__ q, const __bf16* __restrict__ k,
                const __bf16* __restrict__ vt, const int* __restrict__ amask,
                __bf16* __restrict__ ctx) {
  const int S = 2048;
  __shared__ float mbuf[4][36][64];  // [wave][elem][lane], 2-way (free)
  const int bid = blockIdx.x;
  const int wave = threadIdx.x >> 6, lane = threadIdx.x & 63;
  const int j = 63 - (bid >> 5);               // strip, heaviest first
  const int bh = (bid & 7) * 4 + ((bid >> 3) & 3);
  const int b = bh >> 4, h = bh & 15;
  const int quad = lane >> 4, l15 = lane & 15;
  const int q0 = j * 32;

  const __bf16* qp  = q  + (size_t)bh * S * 64;
  const __bf16* kp0 = k  + (size_t)bh * S * 64;
  const __bf16* vp0 = vt + (size_t)bh * 64 * S;

  bf16x8 qf[2][2];  // [mt][ks]
#pragma unroll
  for (int mt = 0; mt < 2; mt++)
#pragma unroll
    for (int ks = 0; ks < 2; ks++)
      qf[mt][ks] = *(const bf16x8*)(qp + (size_t)(q0 + mt * 16 + l15) * 64 +
                                    ks * 32 + quad * 8);

  float mrun[2] = {-1.0e30f, -1.0e30f}, lrun[2] = {0.0f, 0.0f};
  floatx4 oacc[2][4] = {};  // [mt][dh-tile]; col(l15)=q, row(quad*4+r)=dh
  const int nch = ((q0 + 31) >> 6) + 1;  // 64-key chunks

  // one chunk of work: QK^T -> V prefetch -> mask -> online softmax (defer)
  // -> pack -> PV.  kf preloaded by the caller one iteration ahead.
  auto proc = [&](const bf16x8 (&kf)[2][4], int amv, int c) {
    floatx4 st[4][2] = {};  // [key-tile][q-tile]; col(l15)=q, row(quad*4+r)=key
#pragma unroll
    for (int ks = 0; ks < 2; ks++)
#pragma unroll
      for (int nt = 0; nt < 4; nt++) {
        st[nt][0] = mfma16(kf[ks][nt], qf[0][ks], st[nt][0]);
        st[nt][1] = mfma16(kf[ks][nt], qf[1][ks], st[nt][1]);
      }

    // V prefetch: 8 x 16B in flight across the whole softmax
    bf16x8 vf[2][4];
#pragma unroll
    for (int tp = 0; tp < 2; tp++)
#pragma unroll
      for (int nd = 0; nd < 4; nd++)
        vf[tp][nd] = *(const bf16x8*)(vp0 + c * 64 + tp * 32 + quad * 8 +
                                      (size_t)(nd * 16 + l15) * S);

    unsigned long long pm = __ballot(amv == 0);

    if (pm == 0) {  // no padding (wave-uniform; true for all-ones mask)
      if (c == nch - 1) {
#pragma unroll
        for (int nt = 0; nt < 4; nt++) {
          int keyg = c * 64 + nt * 16 + quad * 4;
#pragma unroll
          for (int r = 0; r < 4; r++)
#pragma unroll
            for (int mt = 0; mt < 2; mt++) {
              bool masked = keyg + r > q0 + mt * 16 + l15;
              st[nt][mt][r] = masked ? MASKVAL : st[nt][mt][r];
            }
        }
      }
    } else {
#pragma unroll
      for (int nt = 0; nt < 4; nt++) {
        int kl = nt * 16 + quad * 4;
        int keyg = c * 64 + kl;
#pragma unroll
        for (int r = 0; r < 4; r++) {
          bool pad = (pm >> (kl + r)) & 1ull;
#pragma unroll
          for (int mt = 0; mt < 2; mt++) {
            bool masked = pad || ((c == nch - 1) &&
                                  (keyg + r > q0 + mt * 16 + l15));
            st[nt][mt][r] = masked ? MASKVAL : st[nt][mt][r];
          }
        }
      }
    }

    // online softmax in log2 domain (per q = l15), tree reductions.
    // T13 defer-max: skip rescale while the tile max grows by <= 8 (2^8).
#pragma unroll
    for (int mt = 0; mt < 2; mt++) {
      float m4[4];
#pragma unroll
      for (int nt = 0; nt < 4; nt++)
        m4[nt] = fmaxf(fmaxf(st[nt][mt][0], st[nt][mt][1]),
                       fmaxf(st[nt][mt][2], st[nt][mt][3]));
      float rm = fmaxf(fmaxf(m4[0], m4[1]), fmaxf(m4[2], m4[3]));
      rm = fmaxf(rm, __shfl_xor(rm, 16, 64));
      rm = fmaxf(rm, __shfl_xor(rm, 32, 64));
      if (!__all(rm - mrun[mt] <= 8.0f)) {  // wave-uniform branch
        float mnew = fmaxf(mrun[mt], rm);
        float al = exp2f(mrun[mt] - mnew);
        mrun[mt] = mnew;
        lrun[mt] *= al;
#pragma unroll
        for (int nd = 0; nd < 4; nd++)
#pragma unroll
          for (int r = 0; r < 4; r++) oacc[mt][nd][r] *= al;
      }
      float s4[4];
#pragma unroll
      for (int nt = 0; nt < 4; nt++) {
        float p0v = exp2f(st[nt][mt][0] - mrun[mt]);
        float p1v = exp2f(st[nt][mt][1] - mrun[mt]);
        float p2v = exp2f(st[nt][mt][2] - mrun[mt]);
        float p3v = exp2f(st[nt][mt][3] - mrun[mt]);
        st[nt][mt][0] = p0v; st[nt][mt][1] = p1v;
        st[nt][mt][2] = p2v; st[nt][mt][3] = p3v;
        s4[nt] = (p0v + p1v) + (p2v + p3v);
      }
      float rs = (s4[0] + s4[1]) + (s4[2] + s4[3]);
      rs += __shfl_xor(rs, 16, 64);
      rs += __shfl_xor(rs, 32, 64);
      lrun[mt] += rs;
    }

    // pack P tiles (B-operand == C-layout)
    bf16x4 pB[4][2];
#pragma unroll
    for (int nt = 0; nt < 4; nt++)
#pragma unroll
      for (int mt = 0; mt < 2; mt++) {
        bf16x4 pk = {(__bf16)st[nt][mt][0], (__bf16)st[nt][mt][1],
                     (__bf16)st[nt][mt][2], (__bf16)st[nt][mt][3]};
        pB[nt][mt] = pk;
      }

    // O^T += V^T P^T ; one 16B V frag feeds tiles 2tp and 2tp+1
#pragma unroll
    for (int tp = 0; tp < 2; tp++)
#pragma unroll
      for (int nd = 0; nd < 4; nd++) {
        bf16x8 v8 = vf[tp][nd];
        bf16x4 vA0 = {v8[0], v8[1], v8[2], v8[3]};
        bf16x4 vA1 = {v8[4], v8[5], v8[6], v8[7]};
        oacc[0][nd] = mfma_pv(vA0, pB[2 * tp][0], oacc[0][nd]);
        oacc[1][nd] = mfma_pv(vA0, pB[2 * tp][1], oacc[1][nd]);
        oacc[0][nd] = mfma_pv(vA1, pB[2 * tp + 1][0], oacc[0][nd]);
        oacc[1][nd] = mfma_pv(vA1, pB[2 * tp + 1][1], oacc[1][nd]);
      }
  };

#define LOADK(dst, cc)                                                       \
  do {                                                                       \
    const __bf16* kp_ = kp0 + (size_t)(cc) * 4096;                           \
    _Pragma("unroll") for (int ks_ = 0; ks_ < 2; ks_++)                      \
    _Pragma("unroll") for (int nt_ = 0; nt_ < 4; nt_++)                      \
        dst[ks_][nt_] = *(const bf16x8*)(kp_ + (size_t)(nt_ * 16 + l15) * 64 \
                                         + ks_ * 32 + quad * 8);             \
  } while (0)
#define LOADAM(cc) amask[b * S + (cc) * 64 + lane]

  // chunk loop, register-double-buffered (kA/kB named: rule #20, no runtime
  // indexing of ext_vector arrays).  K(c+4)+amask(c+4) issue before proc(c)
  // -> latency hidden under softmax+PV of chunk c.
  bf16x8 kA[2][4], kB[2][4];
  int amA = 0, amB = 0;
  int c = wave;
  if (c < nch) { LOADK(kA, c); amA = LOADAM(c); }
  while (c < nch) {
    if (c + 4 < nch) { LOADK(kB, c + 4); amB = LOADAM(c + 4); }
    proc(kA, amA, c);
    c += 4;
    if (c >= nch) break;
    if (c + 4 < nch) { LOADK(kA, c + 4); amA = LOADAM(c + 4); }
    proc(kB, amB, c);
    c += 4;
  }
#undef LOADK
#undef LOADAM

  // ---- split-K merge, parallel across all 4 waves ----
  // every wave publishes (O, m, l); wave w then combines dh-tile nd == w.
#pragma unroll
  for (int mt = 0; mt < 2; mt++)
#pragma unroll
    for (int nd = 0; nd < 4; nd++)
#pragma unroll
      for (int r = 0; r < 4; r++)
        mbuf[wave][(mt * 4 + nd) * 4 + r][lane] = oacc[mt][nd][r];
#pragma unroll
  for (int mt = 0; mt < 2; mt++) {
    mbuf[wave][32 + mt][lane] = mrun[mt];
    mbuf[wave][34 + mt][lane] = lrun[mt];
  }
  __syncthreads();

  const int nd = wave;  // each wave owns one dh-tile
#pragma unroll
  for (int mt = 0; mt < 2; mt++) {
    float mw[4], lw[4];
#pragma unroll
    for (int w = 0; w < 4; w++) {
      mw[w] = mbuf[w][32 + mt][lane];
      lw[w] = mbuf[w][34 + mt][lane];
    }
    float mstar = fmaxf(fmaxf(mw[0], mw[1]), fmaxf(mw[2], mw[3]));
    float f[4];
    float lsum = 0.0f;
#pragma unroll
    for (int w = 0; w < 4; w++) {
      f[w] = exp2f(mw[w] - mstar);
      lsum += f[w] * lw[w];
    }
    float linv = 1.0f / lsum;
    int s = q0 + mt * 16 + l15;
    float ov[4];
#pragma unroll
    for (int r = 0; r < 4; r++) {
      float v = 0.0f;
#pragma unroll
      for (int w = 0; w < 4; w++)
        v += f[w] * mbuf[w][(mt * 4 + nd) * 4 + r][lane];
      ov[r] = v * linv;
    }
    bf16x4 o = {(__bf16)ov[0], (__bf16)ov[1], (__bf16)ov[2], (__bf16)ov[3]};
    *(bf16x4*)(ctx + ((size_t)(b * 2048 + s)) * 1024 + h * 64 + nd * 16 +
               quad * 4) = o;
  }
}

// ---------------------------------------------------------------------------
extern "C" void kernel_launch(void* const* d_in, const int* in_sizes, int n_in,
                              void* d_out, int out_size, void* d_ws, size_t ws_size,
                              hipStream_t stream) {
  const float* x  = (const float*)d_in[0];
  const int*   am = (const int*)d_in[1];
  const float* Wq = (const float*)d_in[2];
  const float* bq = (const float*)d_in[3];
  const float* Aq = (const float*)d_in[4];
  const float* Bq = (const float*)d_in[5];
  const float* Wp = (const float*)d_in[6];
  const float* bp = (const float*)d_in[7];
  const float* Ap = (const float*)d_in[8];
  const float* Bp = (const float*)d_in[9];

  __bf16* wqkvT = (__bf16*)d_ws;                       // [3072][1024]
  __bf16* wpT   = wqkvT + (size_t)3072 * 1024;         // [1024][1024]
  __bf16* xbf   = wpT   + (size_t)1024 * 1024;         // [4096][1024]
  __bf16* qbuf  = xbf   + (size_t)4096 * 1024;         // [2][16][2048][64] (+kbuf)
  __bf16* vtbuf = qbuf  + (size_t)2 * 4194304;         // [2][16][64][2048] permuted
  __bf16* ctxb  = vtbuf + (size_t)4194304;             // [4096][1024]

  fold_wt2<<<dim3(64, 16), 256, 0, stream>>>(Wq, Aq, Bq, wqkvT,
                                             Wp, Ap, Bp, wpT);
  cast_x<<<4096, 256, 0, stream>>>(x, xbf);

  gemm_qkv<<<dim3(32, 24), 256, 0, stream>>>(wqkvT, xbf, bq, qbuf, vtbuf);
  flash_attn<<<2048, 256, 0, stream>>>(qbuf, qbuf + 4194304, vtbuf, am, ctxb);
  gemm_proj<<<dim3(8, 64), 256, 0, stream>>>(ctxb, wpT, bp, (float*)d_out, 1024);
}

// Round 2
// 206.295 us; speedup vs baseline: 1.2121x; 1.2121x over previous
//
#include <hip/hip_runtime.h>
#include <hip/hip_bf16.h>

#define LOG2E 1.4426950408889634f
// reference: mask(-1e9) BEFORE scale(/8); log2e folded into Q pre-scale
#define MASKVAL (-1.25e8f * LOG2E)

typedef __bf16 bf16x8 __attribute__((ext_vector_type(8)));
typedef __bf16 bf16x4 __attribute__((ext_vector_type(4)));
typedef short  shortx4 __attribute__((ext_vector_type(4)));
typedef float  floatx4 __attribute__((ext_vector_type(4)));

__device__ __forceinline__ floatx4 mfma16(bf16x8 a, bf16x8 b, floatx4 c) {
  return __builtin_amdgcn_mfma_f32_16x16x32_bf16(a, b, c, 0, 0, 0);
}

// 16x16x16 bf16 MFMA: B-operand layout (n=l15, k=quad*4+i) == S^T C-tile
// layout -> P feeds PV with zero cross-lane transforms.
__device__ __forceinline__ floatx4 mfma_pv(bf16x4 a, bf16x4 b, floatx4 c) {
#if __has_builtin(__builtin_amdgcn_mfma_f32_16x16x16_bf16)
  return __builtin_amdgcn_mfma_f32_16x16x16_bf16(a, b, c, 0, 0, 0);
#else
  shortx4 as, bs;
  __builtin_memcpy(&as, &a, 8);
  __builtin_memcpy(&bs, &b, 8);
  return __builtin_amdgcn_mfma_f32_16x16x16bf16_1k(as, bs, c, 0, 0, 0);
#endif
}

// async global->LDS, 16B per lane. Dest = wave-uniform base + lane*16.
__device__ __forceinline__ void load_lds16(const __bf16* g, __bf16* l) {
  __builtin_amdgcn_global_load_lds(
      (const __attribute__((address_space(1))) void*)g,
      (__attribute__((address_space(3))) void*)l, 16, 0, 0);
}

// ---------------------------------------------------------------------------
// Fold LoRA into weights, emit W_eff^T bf16 [ncols][1024].  Both weight sets
// in one launch: blockIdx.x < 48 -> qkv (ncols 3072), else proj (ncols 1024).
// ---------------------------------------------------------------------------
__global__ __launch_bounds__(256)
void fold_wt2(const float* __restrict__ Wq, const float* __restrict__ Aq,
              const float* __restrict__ Bq, __bf16* __restrict__ WTq,
              const float* __restrict__ Wp, const float* __restrict__ Ap,
              const float* __restrict__ Bp, __bf16* __restrict__ WTp) {
  __shared__ float tile[64][65];
  __shared__ float sLb[8][64];
  const int bx = blockIdx.x;
  const bool isQ = bx < 48;
  const float* W  = isQ ? Wq : Wp;
  const float* La = isQ ? Aq : Ap;
  const float* Lb = isQ ? Bq : Bp;
  __bf16* WT = isQ ? WTq : WTp;
  const int ncols = isQ ? 3072 : 1024;
  const int nt = (isQ ? bx : bx - 48) * 64;
  const int kt = blockIdx.y * 64;
  const int tid = threadIdx.x;
  const int tx = tid & 63, ty = tid >> 6;

  float rLa[8];
  *(float4*)&rLa[0] = *(const float4*)(La + (size_t)(kt + tx) * 8);
  *(float4*)&rLa[4] = *(const float4*)(La + (size_t)(kt + tx) * 8 + 4);

#pragma unroll
  for (int rep = 0; rep < 2; rep++) {
    int idx = tid + rep * 256;
    sLb[idx >> 6][idx & 63] = Lb[(size_t)(idx >> 6) * ncols + nt + (idx & 63)];
  }
#pragma unroll
  for (int rep = 0; rep < 16; rep++) {
    int i = rep * 4 + ty;
    tile[i][tx] = W[(size_t)(kt + i) * ncols + nt + tx];
  }
  __syncthreads();
#pragma unroll
  for (int rep = 0; rep < 16; rep++) {
    int i = rep * 4 + ty;
    int n = nt + i, k = kt + tx;
    float acc = tile[tx][i];
#pragma unroll
    for (int r = 0; r < 8; r++)
      acc += 2.0f * rLa[r] * sLb[r][i];  // LORA_SCALING = 2
    WT[(size_t)n * 1024 + k] = (__bf16)acc;
  }
}

__global__ __launch_bounds__(256)
void cast_x(const float* __restrict__ x, __bf16* __restrict__ o) {
  int i = blockIdx.x * 256 + threadIdx.x;
  float4 v = ((const float4*)x)[i];
  bf16x4 r = {(__bf16)v.x, (__bf16)v.y, (__bf16)v.z, (__bf16)v.w};
  ((bf16x4*)o)[i] = r;
}

// ---------------------------------------------------------------------------
// Fused QKV projection, swapped orientation: D[p][s] = sum_k WT[p][k] X[s][k].
// 128x128 tiles, BK=64, global_load_lds staging, XOR-swizzled LDS.
// Q channels (p<1024) pre-scaled by 0.125*LOG2E.
// V is written to vtb with keys PERMUTED within each 64-key chunk so the
// flash PV A-fragments are 16B-contiguous: key off (t=off>>4, qd=(off>>2)&3,
// r=off&3) stored at position (t>>1)*32 + qd*8 + (t&1)*4 + r.
// ---------------------------------------------------------------------------
__global__ __launch_bounds__(256)
void gemm_qkv(const __bf16* __restrict__ WT, const __bf16* __restrict__ X,
              const float* __restrict__ bias, __bf16* __restrict__ qk,
              __bf16* __restrict__ vtb) {
  const int K = 1024;
  __shared__ alignas(16) __bf16 As[128 * 64];
  __shared__ alignas(16) __bf16 Bs[128 * 64];
  const int tid = threadIdx.x;
  const int wave = tid >> 6, lane = tid & 63;
  const int wm = wave >> 1, wn = wave & 1;
  const int quad = lane >> 4, l15 = lane & 15;
  const int p0 = blockIdx.y * 128, s0 = blockIdx.x * 128;
  const int srow8 = lane >> 3, sc8 = lane & 7;
  const int sswz = sc8 ^ srow8;

  floatx4 acc[4][4] = {};

  for (int kb = 0; kb < K; kb += 64) {
    __syncthreads();
#pragma unroll
    for (int t = 0; t < 4; t++) {
      int rbase = (wave * 4 + t) * 8;
      int row = rbase + srow8;
      load_lds16(WT + (size_t)(p0 + row) * K + kb + sswz * 8, As + rbase * 64);
      load_lds16(X + (size_t)(s0 + row) * K + kb + sswz * 8, Bs + rbase * 64);
    }
    __syncthreads();
#pragma unroll
    for (int ks = 0; ks < 2; ks++) {
      bf16x8 af[4], bfv[4];
#pragma unroll
      for (int t = 0; t < 4; t++) {
        int ra = wm * 64 + t * 16 + l15;
        int rb = wn * 64 + t * 16 + l15;
        int ch = (ks * 4 + quad) ^ (l15 & 7);
        af[t]  = *(const bf16x8*)(As + ra * 64 + ch * 8);
        bfv[t] = *(const bf16x8*)(Bs + rb * 64 + ch * 8);
      }
#pragma unroll
      for (int mi = 0; mi < 4; mi++)
#pragma unroll
        for (int ni = 0; ni < 4; ni++)
          acc[mi][ni] = mfma16(af[mi], bfv[ni], acc[mi][ni]);
    }
  }

  const float qscale = (p0 < 1024) ? 0.125f * LOG2E : 1.0f;  // block-uniform
#pragma unroll
  for (int mi = 0; mi < 4; mi++) {
#pragma unroll
    for (int ni = 0; ni < 4; ni++) {
      int pb = p0 + wm * 64 + mi * 16 + quad * 4;  // channel base (mult of 4)
      int s  = s0 + wn * 64 + ni * 16 + l15;       // token
      int b = s >> 11, s2 = s & 2047;
      if (p0 < 2048) {  // q/k: uniform per block
        int part = pb >> 10, h = (pb & 1023) >> 6, dhb = pb & 63;
        bf16x4 o = {(__bf16)((acc[mi][ni][0] + bias[pb]) * qscale),
                    (__bf16)((acc[mi][ni][1] + bias[pb + 1]) * qscale),
                    (__bf16)((acc[mi][ni][2] + bias[pb + 2]) * qscale),
                    (__bf16)((acc[mi][ni][3] + bias[pb + 3]) * qscale)};
        *(bf16x4*)(qk + (size_t)part * 4194304 +
                   ((size_t)((b * 16 + h) * 2048 + s2)) * 64 + dhb) = o;
      } else {  // v -> v^T with per-chunk key permutation
        int h = (pb & 1023) >> 6, dhb = pb & 63;
        int off = s2 & 63, t = off >> 4, qd = (off >> 2) & 3, rr = off & 3;
        int ps2 = (s2 & ~63) | ((t >> 1) * 32 + qd * 8 + (t & 1) * 4 + rr);
#pragma unroll
        for (int r = 0; r < 4; r++)
          vtb[((size_t)((b * 16 + h) * 64 + dhb + r)) * 2048 + ps2] =
              (__bf16)(acc[mi][ni][r] + bias[pb + r]);
      }
    }
  }
}

// ---------------------------------------------------------------------------
// Output projection, 64x128 tile: grid (8, 64) = 512 blocks.  fp32 out + bias.
// ---------------------------------------------------------------------------
__global__ __launch_bounds__(256)
void gemm_proj(const __bf16* __restrict__ A, const __bf16* __restrict__ BT,
               const float* __restrict__ bias, float* __restrict__ Cout, int N) {
  const int K = 1024;
  __shared__ alignas(16) __bf16 As[64 * 64];
  __shared__ alignas(16) __bf16 Bs[128 * 64];
  const int tid = threadIdx.x;
  const int wave = tid >> 6, lane = tid & 63;
  const int wm = wave >> 1, wn = wave & 1;
  const int quad = lane >> 4, l15 = lane & 15;
  const int m0 = blockIdx.y * 64, n0 = blockIdx.x * 128;
  const int srow8 = lane >> 3, sc8 = lane & 7;
  const int sswz = sc8 ^ srow8;

  floatx4 acc[2][4] = {};

  for (int kb = 0; kb < K; kb += 64) {
    __syncthreads();
#pragma unroll
    for (int t = 0; t < 2; t++) {
      int rbase = (wave * 2 + t) * 8;
      load_lds16(A + (size_t)(m0 + rbase + srow8) * K + kb + sswz * 8,
                 As + rbase * 64);
    }
#pragma unroll
    for (int t = 0; t < 4; t++) {
      int rbase = (wave * 4 + t) * 8;
      load_lds16(BT + (size_t)(n0 + rbase + srow8) * K + kb + sswz * 8,
                 Bs + rbase * 64);
    }
    __syncthreads();
#pragma unroll
    for (int ks = 0; ks < 2; ks++) {
      bf16x8 af[2], bfv[4];
      int ch = (ks * 4 + quad) ^ (l15 & 7);
#pragma unroll
      for (int t = 0; t < 2; t++)
        af[t] = *(const bf16x8*)(As + (wm * 32 + t * 16 + l15) * 64 + ch * 8);
#pragma unroll
      for (int t = 0; t < 4; t++)
        bfv[t] = *(const bf16x8*)(Bs + (wn * 64 + t * 16 + l15) * 64 + ch * 8);
#pragma unroll
      for (int mi = 0; mi < 2; mi++)
#pragma unroll
        for (int ni = 0; ni < 4; ni++)
          acc[mi][ni] = mfma16(af[mi], bfv[ni], acc[mi][ni]);
    }
  }

#pragma unroll
  for (int mi = 0; mi < 2; mi++)
#pragma unroll
    for (int ni = 0; ni < 4; ni++) {
      int n = n0 + wn * 64 + ni * 16 + l15;
#pragma unroll
      for (int r = 0; r < 4; r++) {
        int m = m0 + wm * 32 + mi * 16 + quad * 4 + r;
        Cout[(size_t)m * N + n] = acc[mi][ni][r] + bias[n];
      }
    }
}

// ---------------------------------------------------------------------------
// Causal flash attention v13: 64-q blocks aligned to 64-key chunks.
// KEY PROPERTY: all four 16-q tiles of a 64q-aligned block have the SAME
// causal chunk count nch = jb+1 -> 4 waves run in perfect lockstep, each
// owning one 16-q tile for the WHOLE key range.  No split-K, no merge.
// K/V chunks staged in LDS via global_load_lds (gemm-style XOR swizzle),
// shared by all 4 waves (4x less L2 traffic), double-buffered with counted
// vmcnt(4) (T4) so stage(c+1) flies under compute(c).  Raw s_barrier (not
// __syncthreads) keeps the counted vmcnt alive across the barrier.
// amask word prefetched one chunk ahead BEFORE the DMA issues so it is
// covered by the same counted vmcnt (no vmcnt(0) in the loop).
// Grid: 1024 blocks = exactly 4/CU (fully resident).  jb quartile map makes
// each CU's 4 blocks sum to constant cost (62 chunks) under round-robin
// placement.  VGPR target <=128 (4 waves/SIMD); LDS 32 KB.
// v12 lesson: NO big register double-buffers (occupancy > ILP).
// ---------------------------------------------------------------------------
__global__ __launch_bounds__(256)
void flash_attn(const __bf16* __restrict__ q, const __bf16* __restrict__ k,
                const __bf16* __restrict__ vt, const int* __restrict__ amask,
                __bf16* __restrict__ ctx) {
  const int S = 2048;
  __shared__ alignas(16) __bf16 Ks[2][64 * 64];
  __shared__ alignas(16) __bf16 Vs[2][64 * 64];
  const int bid = blockIdx.x;
  const int g = bid >> 5;            // 0..31 strip group
  const int bh = bid & 31;
  const int u = g & 7, gq = g >> 3;
  // quartile-balanced causal strip map: {31-u, u, 16+u, 15-u} sums to 62
  const int jb = (gq == 0) ? 31 - u : (gq == 1) ? u : (gq == 2) ? 16 + u
                                                                : 15 - u;
  const int b = bh >> 4, h = bh & 15;
  const int wave = threadIdx.x >> 6, lane = threadIdx.x & 63;
  const int quad = lane >> 4, l15 = lane & 15;
  const int Q0 = jb * 64;
  const int qrow = Q0 + wave * 16 + l15;  // this wave's query rows

  const __bf16* qp  = q  + (size_t)bh * S * 64;
  const __bf16* kp0 = k  + (size_t)bh * S * 64;
  const __bf16* vp0 = vt + (size_t)bh * 64 * S;

  const int srow8 = lane >> 3, sc8 = lane & 7;
  const int sswz = sc8 ^ srow8;

  // Q fragments for this wave's 16 rows (issued first -> oldest in vm queue)
  bf16x8 qf[2];
#pragma unroll
  for (int ks = 0; ks < 2; ks++)
    qf[ks] = *(const bf16x8*)(qp + (size_t)qrow * 64 + ks * 32 + quad * 8);

  // amask for chunk 0 BEFORE the DMA -> covered by first counted vmcnt
  int am_cur = amask[b * S + lane];
  int am_nxt = 0;

  // stage chunk cc into buffer bb: each wave stages 16 rows of K and V.
  // K chunk rows = keys (contiguous 4096 elems); V chunk rows = dh
  // (row stride S).  XOR pre-swizzled global source, linear LDS dest.
  auto STAGE = [&](int bb, int cc) {
#pragma unroll
    for (int t = 0; t < 2; t++) {
      int rbase = (wave * 2 + t) * 8;
      load_lds16(kp0 + (size_t)cc * 4096 + (size_t)(rbase + srow8) * 64 +
                     sswz * 8,
                 &Ks[bb][rbase * 64]);
    }
#pragma unroll
    for (int t = 0; t < 2; t++) {
      int rbase = (wave * 2 + t) * 8;
      load_lds16(vp0 + (size_t)(rbase + srow8) * S + cc * 64 + sswz * 8,
                 &Vs[bb][rbase * 64]);
    }
  };

  STAGE(0, 0);

  float mrun = -1.0e30f, lrun = 0.0f;
  floatx4 oacc[4] = {};  // [dh-tile]; col(l15)=q, row(quad*4+r)=dh

  for (int c = 0; c <= jb; c++) {
    const int cur = c & 1;
    if (c < jb) {
      am_nxt = amask[b * S + (c + 1) * 64 + lane];  // before DMA: older
      STAGE(cur ^ 1, c + 1);
      asm volatile("s_waitcnt vmcnt(4)" ::: "memory");
    } else {
      asm volatile("s_waitcnt vmcnt(0)" ::: "memory");
    }
    __builtin_amdgcn_s_barrier();          // chunk c data visible to all
    __builtin_amdgcn_sched_barrier(0);     // no ds_read hoist above barrier

    // S^T = K.Q^T: C col(l15)=q, row(quad*4+r)=key
    floatx4 st[4] = {};
    __builtin_amdgcn_s_setprio(1);
#pragma unroll
    for (int ks = 0; ks < 2; ks++) {
      const int ch = (ks * 4 + quad) ^ (l15 & 7);
      bf16x8 kf[4];
#pragma unroll
      for (int nt = 0; nt < 4; nt++)
        kf[nt] = *(const bf16x8*)(&Ks[cur][(nt * 16 + l15) * 64 + ch * 8]);
#pragma unroll
      for (int nt = 0; nt < 4; nt++)
        st[nt] = mfma16(kf[nt], qf[ks], st[nt]);
    }
    __builtin_amdgcn_s_setprio(0);

    unsigned long long pm = __ballot(am_cur == 0);
    if (pm == 0) {  // no padding (wave-uniform; true for all-ones mask)
      if (c == jb) {  // diagonal chunk: local causal mask
#pragma unroll
        for (int nt = 0; nt < 4; nt++) {
          int kl = nt * 16 + quad * 4;
#pragma unroll
          for (int r = 0; r < 4; r++) {
            bool masked = kl + r > wave * 16 + l15;
            st[nt][r] = masked ? MASKVAL : st[nt][r];
          }
        }
      }
    } else {
#pragma unroll
      for (int nt = 0; nt < 4; nt++) {
        int kl = nt * 16 + quad * 4;
#pragma unroll
        for (int r = 0; r < 4; r++) {
          bool pad = (pm >> (kl + r)) & 1ull;
          bool masked = pad || ((c == jb) && (kl + r > wave * 16 + l15));
          st[nt][r] = masked ? MASKVAL : st[nt][r];
        }
      }
    }

    // online softmax, log2 domain, per q = l15; defer-max (T13, THR=8)
    {
      float m4[4];
#pragma unroll
      for (int nt = 0; nt < 4; nt++)
        m4[nt] = fmaxf(fmaxf(st[nt][0], st[nt][1]),
                       fmaxf(st[nt][2], st[nt][3]));
      float rm = fmaxf(fmaxf(m4[0], m4[1]), fmaxf(m4[2], m4[3]));
      rm = fmaxf(rm, __shfl_xor(rm, 16, 64));
      rm = fmaxf(rm, __shfl_xor(rm, 32, 64));
      if (!__all(rm - mrun <= 8.0f)) {  // wave-uniform branch
        float mnew = fmaxf(mrun, rm);
        float al = exp2f(mrun - mnew);
        mrun = mnew;
        lrun *= al;
#pragma unroll
        for (int nd = 0; nd < 4; nd++)
#pragma unroll
          for (int r = 0; r < 4; r++) oacc[nd][r] *= al;
      }
      float s4[4];
#pragma unroll
      for (int nt = 0; nt < 4; nt++) {
        float p0v = exp2f(st[nt][0] - mrun);
        float p1v = exp2f(st[nt][1] - mrun);
        float p2v = exp2f(st[nt][2] - mrun);
        float p3v = exp2f(st[nt][3] - mrun);
        st[nt][0] = p0v; st[nt][1] = p1v;
        st[nt][2] = p2v; st[nt][3] = p3v;
        s4[nt] = (p0v + p1v) + (p2v + p3v);
      }
      float rs = (s4[0] + s4[1]) + (s4[2] + s4[3]);
      rs += __shfl_xor(rs, 16, 64);
      rs += __shfl_xor(rs, 32, 64);
      lrun += rs;
    }

    // pack P tiles (B-operand == C-layout)
    bf16x4 pB[4];
#pragma unroll
    for (int nt = 0; nt < 4; nt++) {
      bf16x4 pk = {(__bf16)st[nt][0], (__bf16)st[nt][1],
                   (__bf16)st[nt][2], (__bf16)st[nt][3]};
      pB[nt] = pk;
    }

    // O^T += V^T P^T ; one 16B V frag feeds key-subtiles 2tp and 2tp+1
    __builtin_amdgcn_s_setprio(1);
#pragma unroll
    for (int tp = 0; tp < 2; tp++) {
      const int chv = (tp * 4 + quad) ^ (l15 & 7);
#pragma unroll
      for (int nd = 0; nd < 4; nd++) {
        bf16x8 v8 = *(const bf16x8*)(&Vs[cur][(nd * 16 + l15) * 64 + chv * 8]);
        bf16x4 vA0 = {v8[0], v8[1], v8[2], v8[3]};
        bf16x4 vA1 = {v8[4], v8[5], v8[6], v8[7]};
        oacc[nd] = mfma_pv(vA0, pB[2 * tp], oacc[nd]);
        oacc[nd] = mfma_pv(vA1, pB[2 * tp + 1], oacc[nd]);
      }
    }
    __builtin_amdgcn_s_setprio(0);

    am_cur = am_nxt;
    __builtin_amdgcn_s_barrier();  // all waves done reading buf cur
  }

  // epilogue: direct normalize + store (no merge).  1/lrun exact under
  // defer-max (P and lrun share the same mrun reference).
  const float linv = 1.0f / lrun;
#pragma unroll
  for (int nd = 0; nd < 4; nd++) {
    bf16x4 o = {(__bf16)(oacc[nd][0] * linv), (__bf16)(oacc[nd][1] * linv),
                (__bf16)(oacc[nd][2] * linv), (__bf16)(oacc[nd][3] * linv)};
    *(bf16x4*)(ctx + ((size_t)(b * 2048 + qrow)) * 1024 + h * 64 + nd * 16 +
               quad * 4) = o;
  }
}

// ---------------------------------------------------------------------------
extern "C" void kernel_launch(void* const* d_in, const int* in_sizes, int n_in,
                              void* d_out, int out_size, void* d_ws, size_t ws_size,
                              hipStream_t stream) {
  const float* x  = (const float*)d_in[0];
  const int*   am = (const int*)d_in[1];
  const float* Wq = (const float*)d_in[2];
  const float* bq = (const float*)d_in[3];
  const float* Aq = (const float*)d_in[4];
  const float* Bq = (const float*)d_in[5];
  const float* Wp = (const float*)d_in[6];
  const float* bp = (const float*)d_in[7];
  const float* Ap = (const float*)d_in[8];
  const float* Bp = (const float*)d_in[9];

  __bf16* wqkvT = (__bf16*)d_ws;                       // [3072][1024]
  __bf16* wpT   = wqkvT + (size_t)3072 * 1024;         // [1024][1024]
  __bf16* xbf   = wpT   + (size_t)1024 * 1024;         // [4096][1024]
  __bf16* qbuf  = xbf   + (size_t)4096 * 1024;         // [2][16][2048][64] (+kbuf)
  __bf16* vtbuf = qbuf  + (size_t)2 * 4194304;         // [2][16][64][2048] permuted
  __bf16* ctxb  = vtbuf + (size_t)4194304;             // [4096][1024]

  fold_wt2<<<dim3(64, 16), 256, 0, stream>>>(Wq, Aq, Bq, wqkvT,
                                             Wp, Ap, Bp, wpT);
  cast_x<<<4096, 256, 0, stream>>>(x, xbf);

  gemm_qkv<<<dim3(32, 24), 256, 0, stream>>>(wqkvT, xbf, bq, qbuf, vtbuf);
  flash_attn<<<1024, 256, 0, stream>>>(qbuf, qbuf + 4194304, vtbuf, am, ctxb);
  gemm_proj<<<dim3(8, 64), 256, 0, stream>>>(ctxb, wpT, bp, (float*)d_out, 1024);
}